// Round 11
// baseline (186.314 us; speedup 1.0000x reference)
//
#include <hip/hip_runtime.h>
#include <cstddef>

// TAGConv K=2: out = concat(x, m1, m2) @ W^T + b
// R11: (a) remove the 400KB hipMemsetAsync (ran at 10GB/s, ~42us/replay!) --
// cnt[] replaced by a cursor[] copy of rowptr written in scan3, deg zeroed by
// a tiny kernel; (b) team scatter uses non-temporal loads for the dst/src
// streams so they stop evicting the team's L2-resident col/cursor lines.

#define DFEAT 128
#define NTEAMS 8
#define BPT 128   // blocks per team

typedef __attribute__((ext_vector_type(8))) short short8v;  // 8 bf16 = 4 VGPR
typedef __attribute__((ext_vector_type(4))) float f32x4;

__device__ inline unsigned short f2bf(float f) {   // RNE f32 -> bf16
    unsigned int u;
    __builtin_memcpy(&u, &f, 4);
    unsigned int r = u + 0x7FFFu + ((u >> 16) & 1u);
    return (unsigned short)(r >> 16);
}
__device__ inline float bf2f(unsigned short h) {
    unsigned int u = ((unsigned int)h) << 16;
    float f;
    __builtin_memcpy(&f, &u, 4);
    return f;
}

// ---- zero deg ---------------------------------------------------------------
__global__ void zero_kernel(int4* __restrict__ p, int n4) {
    int i = blockIdx.x * blockDim.x + threadIdx.x;
    if (i < n4) p[i] = make_int4(0, 0, 0, 0);
}

// ---- fp32 -> bf16 pack (4 elems/thread) -------------------------------------
__global__ void conv_bf16_kernel(const float* __restrict__ in,
                                 unsigned short* __restrict__ outb, int total4) {
    int i = blockIdx.x * blockDim.x + threadIdx.x;
    if (i >= total4) return;
    const float4 v = reinterpret_cast<const float4*>(in)[i];
    unsigned int w0 = (unsigned int)f2bf(v.x) | ((unsigned int)f2bf(v.y) << 16);
    unsigned int w1 = (unsigned int)f2bf(v.z) | ((unsigned int)f2bf(v.w) << 16);
    reinterpret_cast<uint2*>(outb)[i] = make_uint2(w0, w1);
}

// ---- pack W (fp32 [128][384]) into MFMA-fragment-ordered bf16 ---------------
__global__ void pack_w_kernel(const float* __restrict__ W,
                              unsigned short* __restrict__ Wpk) {
    const int idx = blockIdx.x * blockDim.x + threadIdx.x;   // 12*8*64 = 6144
    if (idx >= 6144) return;
    const int lane = idx & 63;
    const int nt = (idx >> 6) & 7;
    const int ks = idx >> 9;
    const int col = nt * 16 + (lane & 15);
    const int k = ks * 32 + (lane >> 4) * 8;
    const float* wp = W + (size_t)col * 384 + k;
    unsigned int w[4];
#pragma unroll
    for (int j = 0; j < 4; ++j) {
        w[j] = (unsigned int)f2bf(wp[2 * j]) |
               ((unsigned int)f2bf(wp[2 * j + 1]) << 16);
    }
    *reinterpret_cast<uint4*>(Wpk + (size_t)idx * 8) = make_uint4(w[0], w[1], w[2], w[3]);
}

// ---- int histogram of dst ---------------------------------------------------
__global__ void hist_kernel(const int* __restrict__ dst, int* __restrict__ deg, int E) {
    int e = blockIdx.x * blockDim.x + threadIdx.x;
    if (e < E) atomicAdd(&deg[dst[e]], 1);
}

// ---- scan stage 1 -----------------------------------------------------------
__global__ __launch_bounds__(256) void scan1_kernel(const int* __restrict__ deg,
                                                    int* __restrict__ partial,
                                                    int* __restrict__ blockSums,
                                                    float* __restrict__ inv, int N) {
    __shared__ int s[256];
    const int t = threadIdx.x;
    const int i = blockIdx.x * 256 + t;
    const int v = (i < N) ? deg[i] : 0;
    s[t] = v;
    __syncthreads();
#pragma unroll
    for (int off = 1; off < 256; off <<= 1) {
        int x = (t >= off) ? s[t - off] : 0;
        __syncthreads();
        s[t] += x;
        __syncthreads();
    }
    if (i < N) {
        partial[i] = s[t] - v;
        inv[i] = 1.0f / (float)max(v, 1);
    }
    if (t == 255) blockSums[blockIdx.x] = s[255];
}

// ---- scan stage 2 -----------------------------------------------------------
__global__ __launch_bounds__(256) void scan2_kernel(int* __restrict__ blockSums, int nb) {
    __shared__ int s[256];
    const int t = threadIdx.x;
    s[t] = (t < nb) ? blockSums[t] : 0;
    __syncthreads();
#pragma unroll
    for (int off = 1; off < 256; off <<= 1) {
        int x = (t >= off) ? s[t - off] : 0;
        __syncthreads();
        s[t] += x;
        __syncthreads();
    }
    if (t < nb) blockSums[t] = s[t];
}

// ---- scan stage 3: rowptr + cursor copy -------------------------------------
__global__ void scan3_kernel(const int* __restrict__ partial,
                             const int* __restrict__ blockSums,
                             int* __restrict__ rowptr, int* __restrict__ cursor,
                             int N, int E) {
    int i = blockIdx.x * blockDim.x + threadIdx.x;
    if (i < N) {
        int carry = (blockIdx.x > 0) ? blockSums[blockIdx.x - 1] : 0;
        const int rp = partial[i] + carry;
        rowptr[i] = rp;
        cursor[i] = rp;
    }
    if (i == 0) rowptr[N] = E;
}

// ---- team slot scatter ------------------------------------------------------
// Team r = blocks with blockIdx%8==r (XCD r per measured round-robin map;
// perf heuristic only). Team r scans ALL edges and keeps those with dst in
// its 1/8 node range; col/cursor lines stay in one XCD's L2. dst/src reads
// are non-temporal so the streams don't evict col/cursor.
__global__ void csr_scatter_team_kernel(const int* __restrict__ src,
                                        const int* __restrict__ dst,
                                        int* __restrict__ cursor,
                                        int* __restrict__ col, int E, int N) {
    const int r = blockIdx.x & (NTEAMS - 1);
    const int q = blockIdx.x >> 3;
    const int nchunk = (N + NTEAMS - 1) / NTEAMS;
    const int lo = r * nchunk;
    const int hi = min(lo + nchunk, N);
    const int echunk = (E + BPT - 1) / BPT;
    const int e0 = q * echunk;
    const int e1 = min(e0 + echunk, E);
    for (int e = e0 + (int)threadIdx.x; e < e1; e += (int)blockDim.x) {
        const int d = __builtin_nontemporal_load(dst + e);
        if (d >= lo && d < hi) {
            const int s = __builtin_nontemporal_load(src + e);
            const int pos = atomicAdd(&cursor[d], 1);
            col[pos] = s;
        }
    }
}

// ---- bf16 gather: outb[n] = bf16( inv[n] * sum feat[col[e]] ) ---------------
// 16 lanes per node, each lane owns 8 bf16 (16B) of the 256B row.
__global__ __launch_bounds__(256) void gather_bf16_kernel(
    const unsigned short* __restrict__ feat, const int* __restrict__ rowptr,
    const int* __restrict__ col, const float* __restrict__ inv,
    unsigned short* __restrict__ outb, int N) {
    const int n = blockIdx.x * 16 + (threadIdx.x >> 4);
    const int lane = threadIdx.x & 15;
    if (n >= N) return;
    const int beg = rowptr[n];
    const int end = rowptr[n + 1];
    float acc[8];
#pragma unroll
    for (int j = 0; j < 8; ++j) acc[j] = 0.0f;
    int e = beg;
    for (; e + 1 < end; e += 2) {
        const int s0 = col[e];
        const int s1 = col[e + 1];
        const short8v v0 = *reinterpret_cast<const short8v*>(
            feat + (size_t)s0 * DFEAT + lane * 8);
        const short8v v1 = *reinterpret_cast<const short8v*>(
            feat + (size_t)s1 * DFEAT + lane * 8);
#pragma unroll
        for (int j = 0; j < 8; ++j)
            acc[j] += bf2f((unsigned short)v0[j]) + bf2f((unsigned short)v1[j]);
    }
    if (e < end) {
        const int s0 = col[e];
        const short8v v0 = *reinterpret_cast<const short8v*>(
            feat + (size_t)s0 * DFEAT + lane * 8);
#pragma unroll
        for (int j = 0; j < 8; ++j) acc[j] += bf2f((unsigned short)v0[j]);
    }
    const float sc = inv[n];
    unsigned int w[4];
#pragma unroll
    for (int j = 0; j < 4; ++j) {
        w[j] = (unsigned int)f2bf(acc[2 * j] * sc) |
               ((unsigned int)f2bf(acc[2 * j + 1] * sc) << 16);
    }
    *reinterpret_cast<uint4*>(outb + (size_t)n * DFEAT + lane * 8) =
        make_uint4(w[0], w[1], w[2], w[3]);
}

// ---- MFMA GEMM: out[n,c] = b[c] + sum_k h[n,k] * W[c,k] ---------------------
__global__ __launch_bounds__(256) void gemm_mfma_kernel(
    const unsigned short* __restrict__ xb, const unsigned short* __restrict__ m1b,
    const unsigned short* __restrict__ m2b, const unsigned short* __restrict__ Wpk,
    const float* __restrict__ bias, float* __restrict__ out, int N) {
    const int t = threadIdx.x;
    const int w = t >> 6;
    const int l = t & 63;
    const int lr = l & 15;
    const int kg = l >> 4;
    const int rowBase = blockIdx.x * 64 + w * 16;
    int arow = rowBase + lr;
    if (arow >= N) arow = N - 1;      // clamp (duplicate read, store is guarded)

    const short8v* Wv = reinterpret_cast<const short8v*>(Wpk);

    f32x4 acc[8];
#pragma unroll
    for (int nt = 0; nt < 8; ++nt) acc[nt] = (f32x4){0.f, 0.f, 0.f, 0.f};

#pragma unroll
    for (int ks = 0; ks < 12; ++ks) {
        const unsigned short* feat = (ks < 4) ? xb : (ks < 8 ? m1b : m2b);
        const int k0 = (ks & 3) * 32;
        const short8v a = *reinterpret_cast<const short8v*>(
            feat + (size_t)arow * DFEAT + k0 + kg * 8);
        short8v bfrag[8];
#pragma unroll
        for (int nt = 0; nt < 8; ++nt)
            bfrag[nt] = Wv[(ks * 8 + nt) * 64 + l];
#pragma unroll
        for (int nt = 0; nt < 8; ++nt)
            acc[nt] = __builtin_amdgcn_mfma_f32_16x16x32_bf16(a, bfrag[nt], acc[nt], 0, 0, 0);
    }

#pragma unroll
    for (int nt = 0; nt < 8; ++nt) {
        const int c = nt * 16 + lr;
        const float bv = bias[c];
#pragma unroll
        for (int r = 0; r < 4; ++r) {
            const int node = rowBase + kg * 4 + r;
            if (node < N) out[(size_t)node * DFEAT + c] = acc[nt][r] + bv;
        }
    }
}

extern "C" void kernel_launch(void* const* d_in, const int* in_sizes, int n_in,
                              void* d_out, int out_size, void* d_ws, size_t ws_size,
                              hipStream_t stream) {
    (void)n_in; (void)out_size; (void)ws_size;
    const float* x  = (const float*)d_in[0];
    const int*   ei = (const int*)d_in[1];
    const float* W  = (const float*)d_in[2];
    const float* b  = (const float*)d_in[3];
    float* out = (float*)d_out;

    const int N = in_sizes[0] / DFEAT;
    const int E = in_sizes[1] / 2;
    const int* src = ei;
    const int* dst = ei + E;
    const int nb = (N + 255) / 256;

    auto up = [](size_t v) { return (v + 255) & ~(size_t)255; };
    char* p = (char*)d_ws;
    int*   deg       = (int*)p;            p += up((size_t)N * 4);
    int*   cursor    = (int*)p;            p += up((size_t)N * 4);
    int*   partial   = (int*)p;            p += up((size_t)N * 4);
    int*   blockSums = (int*)p;            p += up(256 * 4);
    int*   rowptr    = (int*)p;            p += up(((size_t)N + 1) * 4);
    int*   col       = (int*)p;            p += up((size_t)E * 4);
    float* inv       = (float*)p;          p += up((size_t)N * 4);
    unsigned short* xb  = (unsigned short*)p;  p += up((size_t)N * DFEAT * 2);
    unsigned short* m1b = (unsigned short*)p;  p += up((size_t)N * DFEAT * 2);
    unsigned short* m2b = (unsigned short*)p;  p += up((size_t)N * DFEAT * 2);
    unsigned short* Wpk = (unsigned short*)p;  p += up((size_t)6144 * 8 * 2);

    const int n4 = (N + 3) / 4;   // deg is 256B-aligned; zero n4 int4s
    zero_kernel<<<(n4 + 255) / 256, 256, 0, stream>>>((int4*)deg, n4);

    hist_kernel<<<(E + 255) / 256, 256, 0, stream>>>(dst, deg, E);
    scan1_kernel<<<nb, 256, 0, stream>>>(deg, partial, blockSums, inv, N);
    scan2_kernel<<<1, 256, 0, stream>>>(blockSums, nb);
    scan3_kernel<<<nb, 256, 0, stream>>>(partial, blockSums, rowptr, cursor, N, E);
    csr_scatter_team_kernel<<<NTEAMS * BPT, 256, 0, stream>>>(src, dst, cursor, col, E, N);

    const int x4 = N * DFEAT / 4;
    conv_bf16_kernel<<<(x4 + 255) / 256, 256, 0, stream>>>(x, xb, x4);
    pack_w_kernel<<<(6144 + 255) / 256, 256, 0, stream>>>(W, Wpk);

    const int gatherBlocks = (N + 15) / 16;   // 16 nodes/block (16 lanes each)
    gather_bf16_kernel<<<gatherBlocks, 256, 0, stream>>>(xb,  rowptr, col, inv, m1b, N);
    gather_bf16_kernel<<<gatherBlocks, 256, 0, stream>>>(m1b, rowptr, col, inv, m2b, N);

    gemm_mfma_kernel<<<(N + 63) / 64, 256, 0, stream>>>(xb, m1b, m2b, Wpk, b, out, N);
}